// Round 4
// baseline (279.746 us; speedup 1.0000x reference)
//
#include <hip/hip_runtime.h>

// ---------------------------------------------------------------------------
// loss = 0.5*(ce(hard) + relu(ce(mean)-R)),  logits = (inputs @ features^T)/TEMP
// B=256 rows, D=256, features rows = 131072 (first 65536 = "mean" half).
//
// R8: kill the spill. R7 post-mortem: __launch_bounds__ arg2 behaves as
// WORKGROUPS/CU on this toolchain (R6 (512,4)->64 VGPR, R7 (512,2)->128 VGPR,
// both exact). R7 demand (64 AGPR acc + ~100 arch, unified file) > 128 cap ->
// 47 MB scratch writes, spill reloads serialized the K-loop (outstanding
// bytes/CU ~2.6 KB by Little's law -> 1.76 TB/s only).
//  - 1024 threads = 16 waves; wave = (fs = w&3 feature subset) x (bq = w>>2
//    batch quarter). Per wave per pass: 32 features x 64 batch rows ->
//    acc[2] x f32x16 = 32 unified regs. Total demand ~100 < 128 cap.
//  - __launch_bounds__(1024, 1): safe under both arg2 interpretations.
//  - 16 waves/CU doubles TLP for latency hiding. F rows re-read by 4
//    bq-waves: L1/L2 hits (2 MB/CU), HBM still reads F exactly once.
//  - All inputs (256x256) in 128 KB LDS f16, XOR-swizzled, staged once;
//    NO barriers in the main loop; F streams global->VGPR->MFMA
//    (A-operand of mfma_f32_32x32x16_f16, K-contiguous, distance-2
//    rolling prefetch in static reg slots).
//  - Replay-pass FETCH=48MB shows F stays L3-resident across iterations ->
//    floor below the 21 us HBM estimate.
// Predict: WRITE_SIZE <= 2 MB, gemm 28-40 us, MfmaUtil ~15-20%.
// ---------------------------------------------------------------------------

typedef _Float16 half8 __attribute__((ext_vector_type(8)));
typedef float float4v __attribute__((ext_vector_type(4)));
typedef float float2v __attribute__((ext_vector_type(2)));
typedef float float16v __attribute__((ext_vector_type(16)));

#define BROWS 256       // batch rows (M)
#define DDIM 256        // reduction (K)
#define NCOLS 131072    // total feature rows (2N)
#define NHALF 65536
#define NBLOCKS 256     // partial[] column count (finalize contract)
#define THREADS 1024    // 16 waves
#define ROWB 512        // bytes per LDS row (256 f16)

__global__ __launch_bounds__(THREADS, 1)
void gemm_lse_kernel(const float* __restrict__ A,   // [256][256]
                     const float* __restrict__ F,   // [131072][256]
                     float* __restrict__ partial)   // [256][NBLOCKS]
{
    __shared__ __align__(16) char lds[256 * ROWB];  // 128 KB: all inputs, f16

    const int tid  = threadIdx.x;
    const int lane = tid & 63;
    const int w    = tid >> 6;        // wave 0..15
    const int m    = lane & 31;       // MFMA row/col within 32
    const int hi   = lane >> 5;       // k-half 0/1
    const int fs   = w & 3;           // feature subset within pass
    const int bq   = w >> 2;          // batch quarter 0..3
    const int fblk = blockIdx.x;      // feature superblock (512 features)

    // ---- prologue: stage ALL 256 input rows into LDS as f16, swizzled ----
    // thread t: row r = t>>2, k-quarter q = t&3 (64 f32 = 8 chunks of 16B)
    {
        const int r = tid >> 2;
        const int q = tid & 3;
        const float* ap = A + (size_t)r * DDIM + q * 64;
#pragma unroll
        for (int cc = 0; cc < 8; cc++) {
            const float4v a0 = *(const float4v*)(ap + cc * 8);
            const float4v a1 = *(const float4v*)(ap + cc * 8 + 4);
            half8 hh;
            hh[0] = (_Float16)a0[0]; hh[1] = (_Float16)a0[1];
            hh[2] = (_Float16)a0[2]; hh[3] = (_Float16)a0[3];
            hh[4] = (_Float16)a1[0]; hh[5] = (_Float16)a1[1];
            hh[6] = (_Float16)a1[2]; hh[7] = (_Float16)a1[3];
            const int ck = q * 8 + cc;                     // 16B chunk 0..31
            *(half8*)(lds + r * ROWB + ((ck ^ (r & 7)) << 4)) = hh;
        }
    }
    __syncthreads();   // the ONLY barrier before the reduction epilogue

    float rowsum[2] = {0.f, 0.f};

#pragma unroll 1
    for (int p = 0; p < 4; p++) {
        // this pass: features f0..f0+31 (A-op), batch bq*64..+64 (B-op)
        const int f0 = fblk * 512 + p * 128 + fs * 32 + m;
        const float* fp = F + (size_t)f0 * DDIM + hi * 8;

        float16v acc[2];
#pragma unroll
        for (int nb = 0; nb < 2; nb++)
#pragma unroll
            for (int i = 0; i < 16; i++) acc[nb][i] = 0.f;

        // K loop: 16 steps of K=16; rolling distance-2 prefetch, static slots
        float4v pa0 = *(const float4v*)(fp);
        float4v pb0 = *(const float4v*)(fp + 4);
        float4v pa1 = *(const float4v*)(fp + 16);
        float4v pb1 = *(const float4v*)(fp + 20);

#pragma unroll
        for (int kb = 0; kb < 16; kb += 2) {
            // ---- step kb (slot 0) ----
            {
                const float4v c0 = pa0, c1 = pb0;
                if (kb + 2 < 16) {
                    pa0 = *(const float4v*)(fp + (kb + 2) * 16);
                    pb0 = *(const float4v*)(fp + (kb + 2) * 16 + 4);
                }
                half8 af;   // A-frag: F[f0][kb*16 + hi*8 + j]
                af[0] = (_Float16)c0[0]; af[1] = (_Float16)c0[1];
                af[2] = (_Float16)c0[2]; af[3] = (_Float16)c0[3];
                af[4] = (_Float16)c1[0]; af[5] = (_Float16)c1[1];
                af[6] = (_Float16)c1[2]; af[7] = (_Float16)c1[3];
#pragma unroll
                for (int nb = 0; nb < 2; nb++) {
                    const int bl = bq * 64 + nb * 32 + m;    // batch row
                    const int ck = kb * 2 + hi;              // 16B chunk
                    const half8 bf = *(const half8*)(lds + bl * ROWB + ((ck ^ (bl & 7)) << 4));
                    acc[nb] = __builtin_amdgcn_mfma_f32_32x32x16_f16(af, bf, acc[nb], 0, 0, 0);
                }
            }
            // ---- step kb+1 (slot 1) ----
            {
                const float4v c0 = pa1, c1 = pb1;
                if (kb + 3 < 16) {
                    pa1 = *(const float4v*)(fp + (kb + 3) * 16);
                    pb1 = *(const float4v*)(fp + (kb + 3) * 16 + 4);
                }
                half8 af;
                af[0] = (_Float16)c0[0]; af[1] = (_Float16)c0[1];
                af[2] = (_Float16)c0[2]; af[3] = (_Float16)c0[3];
                af[4] = (_Float16)c1[0]; af[5] = (_Float16)c1[1];
                af[6] = (_Float16)c1[2]; af[7] = (_Float16)c1[3];
#pragma unroll
                for (int nb = 0; nb < 2; nb++) {
                    const int bl = bq * 64 + nb * 32 + m;
                    const int ck = (kb + 1) * 2 + hi;
                    const half8 bf = *(const half8*)(lds + bl * ROWB + ((ck ^ (bl & 7)) << 4));
                    acc[nb] = __builtin_amdgcn_mfma_f32_32x32x16_f16(af, bf, acc[nb], 0, 0, 0);
                }
            }
        }

        // epilogue: exp(logit - 20); only col identity (batch = lane&31) used
#pragma unroll
        for (int nb = 0; nb < 2; nb++)
#pragma unroll
            for (int r = 0; r < 16; r++)
                rowsum[nb] += __expf(fmaf(acc[nb][r], 20.f, -20.f));
    }

    // fold k-halves: lanes l and l^32 hold complementary feature subsets
#pragma unroll
    for (int nb = 0; nb < 2; nb++)
        rowsum[nb] += __shfl_xor(rowsum[nb], 32);

    // block reduction: 4 fs-waves contribute to each batch row; LDS atomics
    __syncthreads();                 // everyone done reading inputs LDS
    float* sums = (float*)lds;       // reuse LDS: sums[256] by batch row
    if (tid < 256) sums[tid] = 0.f;
    __syncthreads();
    if (hi == 0) {
#pragma unroll
        for (int nb = 0; nb < 2; nb++)
            atomicAdd(&sums[bq * 64 + nb * 32 + m], rowsum[nb]);
    }
    __syncthreads();
    if (tid < 256)
        partial[(size_t)tid * NBLOCKS + fblk] = sums[tid];
}

// One block per batch row, 64 threads: per-row CE terms -> ce[b] = {cem, ceh}.
__global__ __launch_bounds__(64)
void finalize_rows(const float* __restrict__ partial,  // [256][NBLOCKS]
                   const float* __restrict__ A,
                   const float* __restrict__ F,
                   const int* __restrict__ targets,
                   float2v* __restrict__ ce)           // [256]
{
    const int b = blockIdx.x;
    const int l = threadIdx.x;   // 0..63

    // partials row: 256 floats; lane l sums one float4.
    // p4[0..31] = mean half (blocks 0..127), p4[32..63] = hard half.
    const float4v* p4 = (const float4v*)(partial + b * NBLOCKS);
    const float4v x = p4[l];
    const float s = x[0] + x[1] + x[2] + x[3];
    float smv = (l < 32) ? s : 0.f;
    float shv = (l < 32) ? 0.f : s;

    // target-logit dots: lane l covers D-elements [4l, 4l+4)
    const int t = targets[b];
    const float4v a  = *(const float4v*)(A + b * DDIM + l * 4);
    const float4v xm = *(const float4v*)(F + (size_t)t * DDIM + l * 4);
    const float4v xh = *(const float4v*)(F + (size_t)(t + NHALF) * DDIM + l * 4);
    float dm = a[0] * xm[0] + a[1] * xm[1] + a[2] * xm[2] + a[3] * xm[3];
    float dh = a[0] * xh[0] + a[1] * xh[1] + a[2] * xh[2] + a[3] * xh[3];

#pragma unroll
    for (int msk = 1; msk < 64; msk <<= 1) {
        smv += __shfl_xor(smv, msk);
        shv += __shfl_xor(shv, msk);
        dm  += __shfl_xor(dm, msk);
        dh  += __shfl_xor(dh, msk);
    }
    if (l == 0) {
        // CE = LSE - target_logit ; LSE = 20 + ln(sum of exp(logit-20))
        float2v r;
        r[0] = 20.f + __logf(smv) - dm * 20.f;
        r[1] = 20.f + __logf(shv) - dh * 20.f;
        ce[b] = r;
    }
}

__global__ __launch_bounds__(256)
void finalize_loss(const float2v* __restrict__ ce,  // [256]
                   float* __restrict__ out)
{
    const float2v c = ce[threadIdx.x];
    float cem = c[0], ceh = c[1];
#pragma unroll
    for (int msk = 1; msk < 64; msk <<= 1) {
        cem += __shfl_xor(cem, msk);
        ceh += __shfl_xor(ceh, msk);
    }
    __shared__ float sb[8];
    const int wv = threadIdx.x >> 6;
    if ((threadIdx.x & 63) == 0) { sb[wv] = cem; sb[4 + wv] = ceh; }
    __syncthreads();
    if (threadIdx.x == 0) {
        const float cm = (sb[0] + sb[1] + sb[2] + sb[3]) * (1.f / 256.f);
        const float ch = (sb[4] + sb[5] + sb[6] + sb[7]) * (1.f / 256.f);
        const float rl = cm - 0.2f;
        out[0] = 0.5f * (ch + (rl > 0.f ? rl : 0.f));
    }
}

extern "C" void kernel_launch(void* const* d_in, const int* in_sizes, int n_in,
                              void* d_out, int out_size, void* d_ws, size_t ws_size,
                              hipStream_t stream) {
    const float* inputs   = (const float*)d_in[0];   // [256,256] f32
    const int*   targets  = (const int*)d_in[1];     // [256] int
    const float* features = (const float*)d_in[2];   // [131072,256] f32
    float* out = (float*)d_out;
    float* partial = (float*)d_ws;                   // 256*NBLOCKS floats = 256 KB
    float2v* ce = (float2v*)((char*)d_ws + BROWS * NBLOCKS * sizeof(float)); // 2 KB

    gemm_lse_kernel<<<NBLOCKS, THREADS, 0, stream>>>(inputs, features, partial);
    finalize_rows<<<BROWS, 64, 0, stream>>>(partial, inputs, features, targets, ce);
    finalize_loss<<<1, 256, 0, stream>>>(ce, out);
}

// Round 5
// 244.254 us; speedup vs baseline: 1.1453x; 1.1453x over previous
//
#include <hip/hip_runtime.h>

// ---------------------------------------------------------------------------
// loss = 0.5*(ce(hard) + relu(ce(mean)-R)),  logits = (inputs @ features^T)/TEMP
// B=256 rows, D=256, features rows = 131072 (first 65536 = "mean" half).
//
// R9: register diet. R8 post-mortem: with 1024-thr blocks the allocator
// ignored launch_bounds (picked 64 arch regs, spilled ~50/thread -> 53 MB
// scratch writes + matching excess fetch; MfmaUtil 4.7%). Only (512,2) has
// a measured, honored 128-reg cap (R7). So: 512 threads AND demand shrunk
// to fit even a pessimistic 64-arch-reg choice:
//  - acc[2] x f32x16 = 32 AGPRs (wave tile 32 features x 64 batch, 8 passes)
//  - two-slot distance-2 prefetch = 16 arch regs; af/bf/addr/misc ~40
//  - full inputs (256x256) f16 XOR-swizzled in 128 KB LDS, staged once;
//    1 block/CU, grid 256 = CU count; NO barriers in the main loop.
//  - F streams global->VGPR->MFMA (A-op of mfma_f32_32x32x16_f16,
//    K-contiguous). 8 waves x 4 KB in flight = 32 KB/CU >> 9.2 KB needed
//    for 6.3 TB/s (Little's law); compute coverage 8x200cy > 900cy latency.
//  - exp(logit-20) folded per pass (logits<=20); only HW-verified C/D
//    col=lane&31 identity consumed (features summed before use).
// Predict: WRITE_SIZE 53 MB -> <2 MB (spill gone), gemm 25-45 us,
// MfmaUtil 15-25%. partial[] layout unchanged -> finalize untouched.
// ---------------------------------------------------------------------------

typedef _Float16 half8 __attribute__((ext_vector_type(8)));
typedef float float4v __attribute__((ext_vector_type(4)));
typedef float float2v __attribute__((ext_vector_type(2)));
typedef float float16v __attribute__((ext_vector_type(16)));

#define BROWS 256       // batch rows (M)
#define DDIM 256        // reduction (K)
#define NCOLS 131072    // total feature rows (2N)
#define NHALF 65536
#define NBLOCKS 256     // partial[] column count (finalize contract)
#define THREADS 512     // 8 waves
#define ROWB 512        // bytes per LDS row (256 f16)

__global__ __launch_bounds__(THREADS, 2)
void gemm_lse_kernel(const float* __restrict__ A,   // [256][256]
                     const float* __restrict__ F,   // [131072][256]
                     float* __restrict__ partial)   // [256][NBLOCKS]
{
    __shared__ __align__(16) char lds[256 * ROWB];  // 128 KB: all inputs, f16

    const int tid  = threadIdx.x;
    const int lane = tid & 63;
    const int w    = tid >> 6;        // wave 0..7
    const int m    = lane & 31;       // MFMA row/col within 32
    const int hi   = lane >> 5;       // k-half 0/1
    const int fh   = w & 1;           // feature half within a 64-feature pass
    const int bq   = w >> 1;          // batch quarter 0..3
    const int fblk = blockIdx.x;      // feature superblock (512 features)

    // ---- prologue: stage ALL 256 input rows into LDS as f16, swizzled ----
    // thread t: row r = t>>1, k-half q = t&1 (128 f32 = 16 chunks of 16B)
    {
        const int r = tid >> 1;
        const int q = tid & 1;
        const float* ap = A + (size_t)r * DDIM + q * 128;
#pragma unroll
        for (int cc = 0; cc < 16; cc++) {
            const float4v a0 = *(const float4v*)(ap + cc * 8);
            const float4v a1 = *(const float4v*)(ap + cc * 8 + 4);
            half8 hh;
            hh[0] = (_Float16)a0[0]; hh[1] = (_Float16)a0[1];
            hh[2] = (_Float16)a0[2]; hh[3] = (_Float16)a0[3];
            hh[4] = (_Float16)a1[0]; hh[5] = (_Float16)a1[1];
            hh[6] = (_Float16)a1[2]; hh[7] = (_Float16)a1[3];
            const int ck = q * 16 + cc;                    // 16B chunk 0..31
            *(half8*)(lds + r * ROWB + ((ck ^ (r & 7)) << 4)) = hh;
        }
    }
    __syncthreads();   // the ONLY barrier before the reduction epilogue

    float rowsum[2] = {0.f, 0.f};

    // LDS row byte-offsets for this wave's two batch sub-tiles (loop-invariant)
    const int ldsrow0 = (bq * 64 + m) * ROWB;
    const int ldsrow1 = (bq * 64 + 32 + m) * ROWB;
    const int sw = (m & 7);           // XOR swizzle key (row&7 == m&7 for both)

#pragma unroll 1
    for (int p = 0; p < 8; p++) {
        // this pass: features f0..f0+31 (A-op), batch bq*64..+64 (B-op)
        const int f0 = fblk * 512 + p * 64 + fh * 32 + m;
        const float* fp = F + (size_t)f0 * DDIM + hi * 8;

        float16v acc[2];
#pragma unroll
        for (int nb = 0; nb < 2; nb++)
#pragma unroll
            for (int i = 0; i < 16; i++) acc[nb][i] = 0.f;

        // K loop: 16 steps of K=16; rolling distance-2 prefetch, static slots
        float4v pa0 = *(const float4v*)(fp);
        float4v pb0 = *(const float4v*)(fp + 4);
        float4v pa1 = *(const float4v*)(fp + 16);
        float4v pb1 = *(const float4v*)(fp + 20);

#pragma unroll
        for (int kb = 0; kb < 16; kb += 2) {
            // ---- step kb (slot 0) ----
            {
                const float4v c0 = pa0, c1 = pb0;
                if (kb + 2 < 16) {
                    pa0 = *(const float4v*)(fp + (kb + 2) * 16);
                    pb0 = *(const float4v*)(fp + (kb + 2) * 16 + 4);
                }
                half8 af;   // A-frag: F[f0][kb*16 + hi*8 + j]
                af[0] = (_Float16)c0[0]; af[1] = (_Float16)c0[1];
                af[2] = (_Float16)c0[2]; af[3] = (_Float16)c0[3];
                af[4] = (_Float16)c1[0]; af[5] = (_Float16)c1[1];
                af[6] = (_Float16)c1[2]; af[7] = (_Float16)c1[3];
                const int ck = kb * 2 + hi;              // 16B chunk
                const half8 bf0 = *(const half8*)(lds + ldsrow0 + ((ck ^ sw) << 4));
                acc[0] = __builtin_amdgcn_mfma_f32_32x32x16_f16(af, bf0, acc[0], 0, 0, 0);
                const half8 bf1 = *(const half8*)(lds + ldsrow1 + ((ck ^ sw) << 4));
                acc[1] = __builtin_amdgcn_mfma_f32_32x32x16_f16(af, bf1, acc[1], 0, 0, 0);
            }
            // ---- step kb+1 (slot 1) ----
            {
                const float4v c0 = pa1, c1 = pb1;
                if (kb + 3 < 16) {
                    pa1 = *(const float4v*)(fp + (kb + 3) * 16);
                    pb1 = *(const float4v*)(fp + (kb + 3) * 16 + 4);
                }
                half8 af;
                af[0] = (_Float16)c0[0]; af[1] = (_Float16)c0[1];
                af[2] = (_Float16)c0[2]; af[3] = (_Float16)c0[3];
                af[4] = (_Float16)c1[0]; af[5] = (_Float16)c1[1];
                af[6] = (_Float16)c1[2]; af[7] = (_Float16)c1[3];
                const int ck = (kb + 1) * 2 + hi;
                const half8 bf0 = *(const half8*)(lds + ldsrow0 + ((ck ^ sw) << 4));
                acc[0] = __builtin_amdgcn_mfma_f32_32x32x16_f16(af, bf0, acc[0], 0, 0, 0);
                const half8 bf1 = *(const half8*)(lds + ldsrow1 + ((ck ^ sw) << 4));
                acc[1] = __builtin_amdgcn_mfma_f32_32x32x16_f16(af, bf1, acc[1], 0, 0, 0);
            }
        }

        // epilogue: exp(logit - 20); only col identity (batch = lane&31) used
#pragma unroll
        for (int nb = 0; nb < 2; nb++)
#pragma unroll
            for (int r = 0; r < 16; r++)
                rowsum[nb] += __expf(fmaf(acc[nb][r], 20.f, -20.f));
    }

    // fold k-halves: lanes l and l^32 hold complementary feature subsets
#pragma unroll
    for (int nb = 0; nb < 2; nb++)
        rowsum[nb] += __shfl_xor(rowsum[nb], 32);

    // block reduction: 2 fh-waves contribute to each batch row; LDS atomics
    __syncthreads();                 // everyone done reading inputs LDS
    float* sums = (float*)lds;       // reuse LDS: sums[256] by batch row
    if (tid < 256) sums[tid] = 0.f;
    __syncthreads();
    if (hi == 0) {
        atomicAdd(&sums[bq * 64 + m], rowsum[0]);
        atomicAdd(&sums[bq * 64 + 32 + m], rowsum[1]);
    }
    __syncthreads();
    if (tid < 256)
        partial[(size_t)tid * NBLOCKS + fblk] = sums[tid];
}

// One block per batch row, 64 threads: per-row CE terms -> ce[b] = {cem, ceh}.
__global__ __launch_bounds__(64)
void finalize_rows(const float* __restrict__ partial,  // [256][NBLOCKS]
                   const float* __restrict__ A,
                   const float* __restrict__ F,
                   const int* __restrict__ targets,
                   float2v* __restrict__ ce)           // [256]
{
    const int b = blockIdx.x;
    const int l = threadIdx.x;   // 0..63

    // partials row: 256 floats; lane l sums one float4.
    // p4[0..31] = mean half (blocks 0..127), p4[32..63] = hard half.
    const float4v* p4 = (const float4v*)(partial + b * NBLOCKS);
    const float4v x = p4[l];
    const float s = x[0] + x[1] + x[2] + x[3];
    float smv = (l < 32) ? s : 0.f;
    float shv = (l < 32) ? 0.f : s;

    // target-logit dots: lane l covers D-elements [4l, 4l+4)
    const int t = targets[b];
    const float4v a  = *(const float4v*)(A + b * DDIM + l * 4);
    const float4v xm = *(const float4v*)(F + (size_t)t * DDIM + l * 4);
    const float4v xh = *(const float4v*)(F + (size_t)(t + NHALF) * DDIM + l * 4);
    float dm = a[0] * xm[0] + a[1] * xm[1] + a[2] * xm[2] + a[3] * xm[3];
    float dh = a[0] * xh[0] + a[1] * xh[1] + a[2] * xh[2] + a[3] * xh[3];

#pragma unroll
    for (int msk = 1; msk < 64; msk <<= 1) {
        smv += __shfl_xor(smv, msk);
        shv += __shfl_xor(shv, msk);
        dm  += __shfl_xor(dm, msk);
        dh  += __shfl_xor(dh, msk);
    }
    if (l == 0) {
        // CE = LSE - target_logit ; LSE = 20 + ln(sum of exp(logit-20))
        float2v r;
        r[0] = 20.f + __logf(smv) - dm * 20.f;
        r[1] = 20.f + __logf(shv) - dh * 20.f;
        ce[b] = r;
    }
}

__global__ __launch_bounds__(256)
void finalize_loss(const float2v* __restrict__ ce,  // [256]
                   float* __restrict__ out)
{
    const float2v c = ce[threadIdx.x];
    float cem = c[0], ceh = c[1];
#pragma unroll
    for (int msk = 1; msk < 64; msk <<= 1) {
        cem += __shfl_xor(cem, msk);
        ceh += __shfl_xor(ceh, msk);
    }
    __shared__ float sb[8];
    const int wv = threadIdx.x >> 6;
    if ((threadIdx.x & 63) == 0) { sb[wv] = cem; sb[4 + wv] = ceh; }
    __syncthreads();
    if (threadIdx.x == 0) {
        const float cm = (sb[0] + sb[1] + sb[2] + sb[3]) * (1.f / 256.f);
        const float ch = (sb[4] + sb[5] + sb[6] + sb[7]) * (1.f / 256.f);
        const float rl = cm - 0.2f;
        out[0] = 0.5f * (ch + (rl > 0.f ? rl : 0.f));
    }
}

extern "C" void kernel_launch(void* const* d_in, const int* in_sizes, int n_in,
                              void* d_out, int out_size, void* d_ws, size_t ws_size,
                              hipStream_t stream) {
    const float* inputs   = (const float*)d_in[0];   // [256,256] f32
    const int*   targets  = (const int*)d_in[1];     // [256] int
    const float* features = (const float*)d_in[2];   // [131072,256] f32
    float* out = (float*)d_out;
    float* partial = (float*)d_ws;                   // 256*NBLOCKS floats = 256 KB
    float2v* ce = (float2v*)((char*)d_ws + BROWS * NBLOCKS * sizeof(float)); // 2 KB

    gemm_lse_kernel<<<NBLOCKS, THREADS, 0, stream>>>(inputs, features, partial);
    finalize_rows<<<BROWS, 64, 0, stream>>>(partial, inputs, features, targets, ce);
    finalize_loss<<<1, 256, 0, stream>>>(ce, out);
}

// Round 6
// 210.432 us; speedup vs baseline: 1.3294x; 1.1607x over previous
//
#include <hip/hip_runtime.h>

// ---------------------------------------------------------------------------
// loss = 0.5*(ce(hard) + relu(ce(mean)-R)),  logits = (inputs @ features^T)/TEMP
// B=256 rows, D=256, features rows = 131072 (first 65536 = "mean" half).
//
// R10: latency fix. R9 post-mortem: spill gone (WRITE 2MB) but MfmaUtil 6.6%,
// HBM 8.8%, VALU 6.9% -> pure latency-bound: distance-2 REGISTER prefetch
// holds 80cy of coverage vs ~600cy L2/L3 latency; per-K-step stall ~500cy.
// Register depth can't reach L/T~15. Fix: F staged through double-buffered
// LDS at PASS granularity (T3-minimum + T14 pattern):
//  - wave w owns batch rows w*32..+31 (all features); per-pass F tile =
//    32 features x 256k f16 = 16 KB, SHARED by all 8 waves, double-buffered.
//    LDS = 128 KB inputs + 2x16 KB F = 160 KB exactly (1 block/CU).
//  - pipeline: at pass p issue global loads for pass p+2 into 16 named regs
//    (coverage = 2 full passes ~1400cy > 900cy HBM-miss latency); compute
//    pass p from LDS (16 MFMA, 2 interleaved accs, NO f32->f16 cvt on the
//    critical path); cvt+ds_write pass p+1 regs; ONE barrier. Loads are
//    consumed before the barrier -> implicit vmcnt(0) drain is free.
//  - XOR swizzle (chunk ^ (row&7)) on both F-tile and inputs tiles; A and B
//    fragments share the same chunk offset per step.
//  - batch row = w*32 + (lane&31): one owner wave per row -> no atomics;
//    fold lane^32 (feature halves) then direct store to partial.
// Predict: gemm 99.7 -> 15-30 us, MfmaUtil 25-40%, WRITE ~2 MB, no spill.
// ---------------------------------------------------------------------------

typedef _Float16 half8 __attribute__((ext_vector_type(8)));
typedef float float4v __attribute__((ext_vector_type(4)));
typedef float float2v __attribute__((ext_vector_type(2)));
typedef float float16v __attribute__((ext_vector_type(16)));

#define BROWS 256       // batch rows (M)
#define DDIM 256        // reduction (K)
#define NCOLS 131072    // total feature rows (2N)
#define NHALF 65536
#define NBLOCKS 256     // partial[] column count (finalize contract)
#define THREADS 512     // 8 waves
#define ROWB 512        // bytes per LDS row (256 f16)
#define FBUF_OFF 131072 // inputs occupy [0,128K); F buffers after
#define FBUF_SZ  16384  // 32 features x 256 k x f16

struct Stage4 { float4v v0, v1, v2, v3; };

__device__ __forceinline__ Stage4 stage_load(const float* __restrict__ p) {
    Stage4 s;
    s.v0 = *(const float4v*)(p);
    s.v1 = *(const float4v*)(p + 4);
    s.v2 = *(const float4v*)(p + 8);
    s.v3 = *(const float4v*)(p + 12);
    return s;
}

__device__ __forceinline__ void stage_write(char* __restrict__ fb, int fr, int sub,
                                            const Stage4& s) {
    half8 h0, h1;
    h0[0] = (_Float16)s.v0[0]; h0[1] = (_Float16)s.v0[1];
    h0[2] = (_Float16)s.v0[2]; h0[3] = (_Float16)s.v0[3];
    h0[4] = (_Float16)s.v1[0]; h0[5] = (_Float16)s.v1[1];
    h0[6] = (_Float16)s.v1[2]; h0[7] = (_Float16)s.v1[3];
    h1[0] = (_Float16)s.v2[0]; h1[1] = (_Float16)s.v2[1];
    h1[2] = (_Float16)s.v2[2]; h1[3] = (_Float16)s.v2[3];
    h1[4] = (_Float16)s.v3[0]; h1[5] = (_Float16)s.v3[1];
    h1[6] = (_Float16)s.v3[2]; h1[7] = (_Float16)s.v3[3];
    const int c0 = sub * 2, c1 = sub * 2 + 1;
    *(half8*)(fb + fr * ROWB + ((c0 ^ (fr & 7)) << 4)) = h0;
    *(half8*)(fb + fr * ROWB + ((c1 ^ (fr & 7)) << 4)) = h1;
}

// one pass: 32 features (from fb) x 32 batch rows (from pB) x K=256
__device__ __forceinline__ void compute_pass(const char* __restrict__ pA,
                                             const char* __restrict__ pB,
                                             int sw, int hi, float& rowsum) {
    float16v a0, a1;
#pragma unroll
    for (int i = 0; i < 16; i++) { a0[i] = 0.f; a1[i] = 0.f; }
#pragma unroll
    for (int kb = 0; kb < 16; kb += 2) {
        {
            const int coff = ((kb * 2 + hi) ^ sw) << 4;
            const half8 af = *(const half8*)(pA + coff);
            const half8 bf = *(const half8*)(pB + coff);
            a0 = __builtin_amdgcn_mfma_f32_32x32x16_f16(af, bf, a0, 0, 0, 0);
        }
        {
            const int coff = (((kb + 1) * 2 + hi) ^ sw) << 4;
            const half8 af = *(const half8*)(pA + coff);
            const half8 bf = *(const half8*)(pB + coff);
            a1 = __builtin_amdgcn_mfma_f32_32x32x16_f16(af, bf, a1, 0, 0, 0);
        }
    }
    // exp(logit-20) fold; only col=lane&31 (batch) identity is consumed
#pragma unroll
    for (int i = 0; i < 16; i++)
        rowsum += __expf(fmaf(a0[i] + a1[i], 20.f, -20.f));
}

__global__ __launch_bounds__(THREADS, 2)
void gemm_lse_kernel(const float* __restrict__ A,   // [256][256]
                     const float* __restrict__ F,   // [131072][256]
                     float* __restrict__ partial)   // [256][NBLOCKS]
{
    __shared__ __align__(16) char lds[FBUF_OFF + 2 * FBUF_SZ];  // 160 KB

    const int tid  = threadIdx.x;
    const int lane = tid & 63;
    const int w    = tid >> 6;        // wave 0..7 -> batch rows w*32..+31
    const int m    = lane & 31;       // MFMA row/col within 32
    const int hi   = lane >> 5;       // k-half 0/1
    const int fblk = blockIdx.x;      // feature superblock (512 features)

    char* fbuf0 = lds + FBUF_OFF;
    char* fbuf1 = fbuf0 + FBUF_SZ;

    // staging map: thread t covers F row fr = t>>4, k f32 [sub*16, +16)
    const int fr  = tid >> 4;
    const int sub = tid & 15;
    const float* fsrc = F + ((size_t)fblk * 512 + fr) * DDIM + sub * 16;

    // ---- issue F loads for passes 0 and 1 first (latency hides under
    //      the inputs staging below) ----
    Stage4 sA = stage_load(fsrc);
    Stage4 sB = stage_load(fsrc + 32 * DDIM);

    // ---- stage ALL 256 input rows into LDS as f16, swizzled ----
    // thread t: row r = t>>1, k-half q = t&1 (128 f32 = 16 chunks of 16B)
    {
        const int r = tid >> 1;
        const int q = tid & 1;
        const float* ap = A + (size_t)r * DDIM + q * 128;
#pragma unroll
        for (int cc = 0; cc < 16; cc++) {
            const float4v a0 = *(const float4v*)(ap + cc * 8);
            const float4v a1 = *(const float4v*)(ap + cc * 8 + 4);
            half8 hh;
            hh[0] = (_Float16)a0[0]; hh[1] = (_Float16)a0[1];
            hh[2] = (_Float16)a0[2]; hh[3] = (_Float16)a0[3];
            hh[4] = (_Float16)a1[0]; hh[5] = (_Float16)a1[1];
            hh[6] = (_Float16)a1[2]; hh[7] = (_Float16)a1[3];
            const int ck = q * 16 + cc;                    // 16B chunk 0..31
            *(half8*)(lds + r * ROWB + ((ck ^ (r & 7)) << 4)) = hh;
        }
    }

    // ---- write pass-0 F tile (sA has had the whole inputs stage to land) ----
    stage_write(fbuf0, fr, sub, sA);
    __syncthreads();

    float rowsum = 0.f;
    const char* pB = lds + (w * 32 + m) * ROWB;   // inputs row for this lane
    const int   sw = m & 7;                       // shared XOR key (row&7==m&7)
    const char* pA0 = fbuf0 + m * ROWB;
    const char* pA1 = fbuf1 + m * ROWB;

    // 16 passes of 32 features; double-buffered, distance-2 load pipeline.
    // even pass pe: compute buf0, write sB->buf1, reload sA<-pe+2
    // odd  pass   : compute buf1, write sA->buf0, reload sB<-pe+3
#pragma unroll 1
    for (int pp = 0; pp < 8; pp++) {
        const int pe = pp * 2;
        if (pe + 2 < 16) sA = stage_load(fsrc + (size_t)(pe + 2) * 32 * DDIM);
        compute_pass(pA0, pB, sw, hi, rowsum);
        stage_write(fbuf1, fr, sub, sB);          // pass pe+1 tile
        __syncthreads();

        if (pe + 3 < 16) sB = stage_load(fsrc + (size_t)(pe + 3) * 32 * DDIM);
        compute_pass(pA1, pB, sw, hi, rowsum);
        if (pe + 2 < 16) {
            stage_write(fbuf0, fr, sub, sA);      // pass pe+2 tile
        }
        __syncthreads();
    }

    // fold feature halves (lanes l, l^32 hold complementary feature rows)
    rowsum += __shfl_xor(rowsum, 32);
    if (hi == 0)
        partial[(size_t)(w * 32 + m) * NBLOCKS + fblk] = rowsum;
}

// One block per batch row, 64 threads: per-row CE terms -> ce[b] = {cem, ceh}.
__global__ __launch_bounds__(64)
void finalize_rows(const float* __restrict__ partial,  // [256][NBLOCKS]
                   const float* __restrict__ A,
                   const float* __restrict__ F,
                   const int* __restrict__ targets,
                   float2v* __restrict__ ce)           // [256]
{
    const int b = blockIdx.x;
    const int l = threadIdx.x;   // 0..63

    // partials row: 256 floats; lane l sums one float4.
    // p4[0..31] = mean half (blocks 0..127), p4[32..63] = hard half.
    const float4v* p4 = (const float4v*)(partial + b * NBLOCKS);
    const float4v x = p4[l];
    const float s = x[0] + x[1] + x[2] + x[3];
    float smv = (l < 32) ? s : 0.f;
    float shv = (l < 32) ? 0.f : s;

    // target-logit dots: lane l covers D-elements [4l, 4l+4)
    const int t = targets[b];
    const float4v a  = *(const float4v*)(A + b * DDIM + l * 4);
    const float4v xm = *(const float4v*)(F + (size_t)t * DDIM + l * 4);
    const float4v xh = *(const float4v*)(F + (size_t)(t + NHALF) * DDIM + l * 4);
    float dm = a[0] * xm[0] + a[1] * xm[1] + a[2] * xm[2] + a[3] * xm[3];
    float dh = a[0] * xh[0] + a[1] * xh[1] + a[2] * xh[2] + a[3] * xh[3];

#pragma unroll
    for (int msk = 1; msk < 64; msk <<= 1) {
        smv += __shfl_xor(smv, msk);
        shv += __shfl_xor(shv, msk);
        dm  += __shfl_xor(dm, msk);
        dh  += __shfl_xor(dh, msk);
    }
    if (l == 0) {
        // CE = LSE - target_logit ; LSE = 20 + ln(sum of exp(logit-20))
        float2v r;
        r[0] = 20.f + __logf(smv) - dm * 20.f;
        r[1] = 20.f + __logf(shv) - dh * 20.f;
        ce[b] = r;
    }
}

__global__ __launch_bounds__(256)
void finalize_loss(const float2v* __restrict__ ce,  // [256]
                   float* __restrict__ out)
{
    const float2v c = ce[threadIdx.x];
    float cem = c[0], ceh = c[1];
#pragma unroll
    for (int msk = 1; msk < 64; msk <<= 1) {
        cem += __shfl_xor(cem, msk);
        ceh += __shfl_xor(ceh, msk);
    }
    __shared__ float sb[8];
    const int wv = threadIdx.x >> 6;
    if ((threadIdx.x & 63) == 0) { sb[wv] = cem; sb[4 + wv] = ceh; }
    __syncthreads();
    if (threadIdx.x == 0) {
        const float cm = (sb[0] + sb[1] + sb[2] + sb[3]) * (1.f / 256.f);
        const float ch = (sb[4] + sb[5] + sb[6] + sb[7]) * (1.f / 256.f);
        const float rl = cm - 0.2f;
        out[0] = 0.5f * (ch + (rl > 0.f ? rl : 0.f));
    }
}

extern "C" void kernel_launch(void* const* d_in, const int* in_sizes, int n_in,
                              void* d_out, int out_size, void* d_ws, size_t ws_size,
                              hipStream_t stream) {
    const float* inputs   = (const float*)d_in[0];   // [256,256] f32
    const int*   targets  = (const int*)d_in[1];     // [256] int
    const float* features = (const float*)d_in[2];   // [131072,256] f32
    float* out = (float*)d_out;
    float* partial = (float*)d_ws;                   // 256*NBLOCKS floats = 256 KB
    float2v* ce = (float2v*)((char*)d_ws + BROWS * NBLOCKS * sizeof(float)); // 2 KB

    gemm_lse_kernel<<<NBLOCKS, THREADS, 0, stream>>>(inputs, features, partial);
    finalize_rows<<<BROWS, 64, 0, stream>>>(partial, inputs, features, targets, ce);
    finalize_loss<<<1, 256, 0, stream>>>(ce, out);
}

// Round 7
// 210.064 us; speedup vs baseline: 1.3317x; 1.0018x over previous
//
#include <hip/hip_runtime.h>

// ---------------------------------------------------------------------------
// loss = 0.5*(ce(hard) + relu(ce(mean)-R)),  logits = (inputs @ features^T)/TEMP
// B=256 rows, D=256, features rows = 131072 (first 65536 = "mean" half).
//
// R11: kill the bf LDS reads. R10 post-mortem: gemm ~66us (dropped out of
// top-5; fill kernels at 77us are harness re-poison, HBM-saturated). R10's
// floor was 2 ds_read_b128 per MFMA (af+bf) = 20.5us CU-serialized LDS +
// per-step lgkmcnt latency at 2 waves/SIMD. Fix: the B-fragment is the
// lane's OWN inputs row (batch = lane&31 = C column, 16 chunks x 16B for
// its k-half = 64 VGPRs) -> hold it in registers for the whole kernel.
//  - 1 ds_read/MFMA (af only): LDS leg 20.5 -> 10.2us, below HBM leg.
//  - distance-1 F staging, issue-at-top: [barrier] issue loads(p+1) ->
//    compute(p) -> wait+write(p+1) -> [barrier]. vmcnt=0 at the barrier
//    naturally (no m97 drain stall); coverage = 1 compute pass ~1500cy
//    > 900cy HBM latency.
//  - no LDS atomics: each batch row has exactly one owner lane.
//  - regs: brow 64 + acc 16 + stage 16 + af 8 + addr ~12 = ~116 < 128
//    (the (512,2) cap measured honored in R7/R9). Fallback if WRITE_SIZE
//    shows spill: halve brow to 8 chunks, read odd-kb bf from LDS.
// Predict: gemm 20-32us, WRITE ~2MB, MfmaUtil 20-30%, total 165-180us.
// ---------------------------------------------------------------------------

typedef _Float16 half8 __attribute__((ext_vector_type(8)));
typedef float float4v __attribute__((ext_vector_type(4)));
typedef float float2v __attribute__((ext_vector_type(2)));
typedef float float16v __attribute__((ext_vector_type(16)));

#define BROWS 256       // batch rows (M)
#define DDIM 256        // reduction (K)
#define NCOLS 131072    // total feature rows (2N)
#define NHALF 65536
#define NBLOCKS 256     // partial[] column count (finalize contract)
#define THREADS 512     // 8 waves
#define ROWB 512        // bytes per LDS row (256 f16)
#define FBUF_OFF 131072 // inputs occupy [0,128K); F buffers after
#define FBUF_SZ  16384  // 32 features x 256 k x f16

struct Stage4 { float4v v0, v1, v2, v3; };

__device__ __forceinline__ Stage4 stage_load(const float* __restrict__ p) {
    Stage4 s;
    s.v0 = *(const float4v*)(p);
    s.v1 = *(const float4v*)(p + 4);
    s.v2 = *(const float4v*)(p + 8);
    s.v3 = *(const float4v*)(p + 12);
    return s;
}

__device__ __forceinline__ void stage_write(char* __restrict__ fb, int fr, int sub,
                                            const Stage4& s) {
    half8 h0, h1;
    h0[0] = (_Float16)s.v0[0]; h0[1] = (_Float16)s.v0[1];
    h0[2] = (_Float16)s.v0[2]; h0[3] = (_Float16)s.v0[3];
    h0[4] = (_Float16)s.v1[0]; h0[5] = (_Float16)s.v1[1];
    h0[6] = (_Float16)s.v1[2]; h0[7] = (_Float16)s.v1[3];
    h1[0] = (_Float16)s.v2[0]; h1[1] = (_Float16)s.v2[1];
    h1[2] = (_Float16)s.v2[2]; h1[3] = (_Float16)s.v2[3];
    h1[4] = (_Float16)s.v3[0]; h1[5] = (_Float16)s.v3[1];
    h1[6] = (_Float16)s.v3[2]; h1[7] = (_Float16)s.v3[3];
    const int c0 = sub * 2, c1 = sub * 2 + 1;
    *(half8*)(fb + fr * ROWB + ((c0 ^ (fr & 7)) << 4)) = h0;
    *(half8*)(fb + fr * ROWB + ((c1 ^ (fr & 7)) << 4)) = h1;
}

__global__ __launch_bounds__(THREADS, 2)
void gemm_lse_kernel(const float* __restrict__ A,   // [256][256]
                     const float* __restrict__ F,   // [131072][256]
                     float* __restrict__ partial)   // [256][NBLOCKS]
{
    __shared__ __align__(16) char lds[FBUF_OFF + 2 * FBUF_SZ];  // 160 KB

    const int tid  = threadIdx.x;
    const int lane = tid & 63;
    const int w    = tid >> 6;        // wave 0..7 -> batch rows w*32..+31
    const int m    = lane & 31;       // MFMA row/col within 32
    const int hi   = lane >> 5;       // k-half 0/1
    const int fblk = blockIdx.x;      // feature superblock (512 features)

    char* fbuf0 = lds + FBUF_OFF;
    char* fbuf1 = fbuf0 + FBUF_SZ;

    // staging map: thread t covers F row fr = t>>4, k f32 [sub*16, +16)
    const int fr  = tid >> 4;
    const int sub = tid & 15;
    const float* fsrc = F + ((size_t)fblk * 512 + fr) * DDIM + sub * 16;

    // ---- issue F loads for pass 0 (hide under inputs staging) ----
    Stage4 sN = stage_load(fsrc);

    // ---- stage ALL 256 input rows into LDS as f16, swizzled ----
    // thread t: row r = t>>1, k-half q = t&1 (128 f32 = 16 chunks of 16B)
    {
        const int r = tid >> 1;
        const int q = tid & 1;
        const float* ap = A + (size_t)r * DDIM + q * 128;
#pragma unroll
        for (int cc = 0; cc < 16; cc++) {
            const float4v a0 = *(const float4v*)(ap + cc * 8);
            const float4v a1 = *(const float4v*)(ap + cc * 8 + 4);
            half8 hh;
            hh[0] = (_Float16)a0[0]; hh[1] = (_Float16)a0[1];
            hh[2] = (_Float16)a0[2]; hh[3] = (_Float16)a0[3];
            hh[4] = (_Float16)a1[0]; hh[5] = (_Float16)a1[1];
            hh[6] = (_Float16)a1[2]; hh[7] = (_Float16)a1[3];
            const int ck = q * 16 + cc;                    // 16B chunk 0..31
            *(half8*)(lds + r * ROWB + ((ck ^ (r & 7)) << 4)) = hh;
        }
    }

    // ---- write pass-0 F tile (sN had the whole inputs stage to land) ----
    stage_write(fbuf0, fr, sub, sN);
    __syncthreads();

    // ---- pull this lane's inputs row chunks into registers (held forever)
    // B-frag for kb step: inputs[w*32+m][k = kb*16 + hi*8 + j] = chunk 2kb+hi
    half8 brow[16];
    {
        const char* myrow = lds + (w * 32 + m) * ROWB;
        const int swm = m & 7;        // (w*32+m)&7 == m&7
#pragma unroll
        for (int kb = 0; kb < 16; kb++)
            brow[kb] = *(const half8*)(myrow + (((2 * kb + hi) ^ swm) << 4));
    }

    float rs0 = 0.f, rs1 = 0.f;
    const int sw = m & 7;
    const char* pA0 = fbuf0 + m * ROWB;   // F-tile row for this lane
    const char* pA1 = fbuf1 + m * ROWB;

    // 16 passes of 32 features; double-buffered; distance-1 issue-at-top.
#pragma unroll 1
    for (int p = 0; p < 16; p++) {
        // (a) issue global loads for pass p+1 right after the barrier
        if (p + 1 < 16) sN = stage_load(fsrc + (size_t)(p + 1) * 32 * DDIM);

        // (b) compute pass p from LDS F-tile + register brow
        const char* pA = (p & 1) ? pA1 : pA0;
        float16v acc;
#pragma unroll
        for (int i = 0; i < 16; i++) acc[i] = 0.f;

        half8 afc = *(const half8*)(pA + ((hi ^ sw) << 4));   // kb=0 chunk
#pragma unroll
        for (int kb = 0; kb < 16; kb++) {
            half8 afn;
            if (kb < 15)
                afn = *(const half8*)(pA + (((2 * (kb + 1) + hi) ^ sw) << 4));
            acc = __builtin_amdgcn_mfma_f32_32x32x16_f16(afc, brow[kb], acc, 0, 0, 0);
            afc = afn;
        }

        // exp(logit-20) fold; only col=lane&31 (batch) identity is consumed
#pragma unroll
        for (int i = 0; i < 16; i += 2) {
            rs0 += __expf(fmaf(acc[i], 20.f, -20.f));
            rs1 += __expf(fmaf(acc[i + 1], 20.f, -20.f));
        }

        // (c) wait + write pass p+1 tile into the other buffer
        if (p + 1 < 16) {
            stage_write((p & 1) ? fbuf0 : fbuf1, fr, sub, sN);
            // (d) barrier: vmcnt already 0 (consumed above) -> no drain stall
            __syncthreads();
        }
    }

    // fold feature halves (lanes l, l^32 hold complementary feature rows)
    float rowsum = rs0 + rs1;
    rowsum += __shfl_xor(rowsum, 32);
    if (hi == 0)
        partial[(size_t)(w * 32 + m) * NBLOCKS + fblk] = rowsum;
}

// One block per batch row, 64 threads: per-row CE terms -> ce[b] = {cem, ceh}.
__global__ __launch_bounds__(64)
void finalize_rows(const float* __restrict__ partial,  // [256][NBLOCKS]
                   const float* __restrict__ A,
                   const float* __restrict__ F,
                   const int* __restrict__ targets,
                   float2v* __restrict__ ce)           // [256]
{
    const int b = blockIdx.x;
    const int l = threadIdx.x;   // 0..63

    // partials row: 256 floats; lane l sums one float4.
    // p4[0..31] = mean half (blocks 0..127), p4[32..63] = hard half.
    const float4v* p4 = (const float4v*)(partial + b * NBLOCKS);
    const float4v x = p4[l];
    const float s = x[0] + x[1] + x[2] + x[3];
    float smv = (l < 32) ? s : 0.f;
    float shv = (l < 32) ? 0.f : s;

    // target-logit dots: lane l covers D-elements [4l, 4l+4)
    const int t = targets[b];
    const float4v a  = *(const float4v*)(A + b * DDIM + l * 4);
    const float4v xm = *(const float4v*)(F + (size_t)t * DDIM + l * 4);
    const float4v xh = *(const float4v*)(F + (size_t)(t + NHALF) * DDIM + l * 4);
    float dm = a[0] * xm[0] + a[1] * xm[1] + a[2] * xm[2] + a[3] * xm[3];
    float dh = a[0] * xh[0] + a[1] * xh[1] + a[2] * xh[2] + a[3] * xh[3];

#pragma unroll
    for (int msk = 1; msk < 64; msk <<= 1) {
        smv += __shfl_xor(smv, msk);
        shv += __shfl_xor(shv, msk);
        dm  += __shfl_xor(dm, msk);
        dh  += __shfl_xor(dh, msk);
    }
    if (l == 0) {
        // CE = LSE - target_logit ; LSE = 20 + ln(sum of exp(logit-20))
        float2v r;
        r[0] = 20.f + __logf(smv) - dm * 20.f;
        r[1] = 20.f + __logf(shv) - dh * 20.f;
        ce[b] = r;
    }
}

__global__ __launch_bounds__(256)
void finalize_loss(const float2v* __restrict__ ce,  // [256]
                   float* __restrict__ out)
{
    const float2v c = ce[threadIdx.x];
    float cem = c[0], ceh = c[1];
#pragma unroll
    for (int msk = 1; msk < 64; msk <<= 1) {
        cem += __shfl_xor(cem, msk);
        ceh += __shfl_xor(ceh, msk);
    }
    __shared__ float sb[8];
    const int wv = threadIdx.x >> 6;
    if ((threadIdx.x & 63) == 0) { sb[wv] = cem; sb[4 + wv] = ceh; }
    __syncthreads();
    if (threadIdx.x == 0) {
        const float cm = (sb[0] + sb[1] + sb[2] + sb[3]) * (1.f / 256.f);
        const float ch = (sb[4] + sb[5] + sb[6] + sb[7]) * (1.f / 256.f);
        const float rl = cm - 0.2f;
        out[0] = 0.5f * (ch + (rl > 0.f ? rl : 0.f));
    }
}

extern "C" void kernel_launch(void* const* d_in, const int* in_sizes, int n_in,
                              void* d_out, int out_size, void* d_ws, size_t ws_size,
                              hipStream_t stream) {
    const float* inputs   = (const float*)d_in[0];   // [256,256] f32
    const int*   targets  = (const int*)d_in[1];     // [256] int
    const float* features = (const float*)d_in[2];   // [131072,256] f32
    float* out = (float*)d_out;
    float* partial = (float*)d_ws;                   // 256*NBLOCKS floats = 256 KB
    float2v* ce = (float2v*)((char*)d_ws + BROWS * NBLOCKS * sizeof(float)); // 2 KB

    gemm_lse_kernel<<<NBLOCKS, THREADS, 0, stream>>>(inputs, features, partial);
    finalize_rows<<<BROWS, 64, 0, stream>>>(partial, inputs, features, targets, ce);
    finalize_loss<<<1, 256, 0, stream>>>(ce, out);
}

// Round 10
// 205.536 us; speedup vs baseline: 1.3611x; 1.0220x over previous
//
#include <hip/hip_runtime.h>

// ---------------------------------------------------------------------------
// loss = 0.5*(ce(hard) + relu(ce(mean)-R)),  logits = (inputs @ features^T)/TEMP
// B=256 rows, D=256, features rows = 131072 (first 65536 = "mean" half).
//
// R12/R14: line-contiguous staging. R10 vs R11 A/B (2 vs 1 ds_read/MFMA,
// both ~66us) proved LDS reads are NOT the limiter. Achieved F-feed = 2.0
// TB/s vs 6.9 TB/s the harness fill sustains -> feed-rate wall. Common
// factor of all slow variants: every global load instr was 64 lanes x 16B
// at >=64B stride = 64 distinct cache lines per instruction (1/4-used).
// Fix: wave w stages F rows p*32+w*4+i (i=0..3), lane l takes 16B chunk
// l -> each global_load_dwordx4 covers ONE contiguous 1KB row (16 lines,
// 4 lanes/line, fully used). Same LDS bytes/swizzle as R11 -> compute side
// untouched.
// R14 BUGFIX vs R12 (NaN): inputs prologue staged only rows 0..127 (loop
// bound half<2 -> j=half*8+i in 0..15 -> rows j*8+w < 128); waves 4-7 read
// uninitialized LDS into brow. Fix: 4 groups (g<4) -> j in 0..31 -> all
// 256 rows staged. Everything else identical to R12.
//  - sched_barrier(0) between compute and stage_write: stops the compiler
//    hoisting the cvt (and its implicit vmcnt wait) above the MFMA loop.
//  - structure otherwise = R11: inputs f16 in 128KB LDS + brow in 64 VGPRs
//    (1 ds_read/MFMA), F double-buffered 2x16KB, distance-1 issue-at-top,
//    one barrier per pass, no atomics.
// Predict: gemm 66 -> 25-35us (feed 4-5.5 TB/s), total 210 -> 170-182us.
// If total unchanged: theory falsified -> pivot to 3-buffer counted-vmcnt.
// ---------------------------------------------------------------------------

typedef _Float16 half8 __attribute__((ext_vector_type(8)));
typedef _Float16 half4v __attribute__((ext_vector_type(4)));
typedef float float4v __attribute__((ext_vector_type(4)));
typedef float float2v __attribute__((ext_vector_type(2)));
typedef float float16v __attribute__((ext_vector_type(16)));

#define BROWS 256       // batch rows (M)
#define DDIM 256        // reduction (K)
#define NCOLS 131072    // total feature rows (2N)
#define NHALF 65536
#define NBLOCKS 256     // partial[] column count (finalize contract)
#define THREADS 512     // 8 waves
#define ROWB 512        // bytes per LDS row (256 f16)
#define FBUF_OFF 131072 // inputs occupy [0,128K); F buffers after
#define FBUF_SZ  16384  // 32 features x 256 k x f16

__device__ __forceinline__ half4v cvt4(const float4v x) {
    half4v h;
    h[0] = (_Float16)x[0]; h[1] = (_Float16)x[1];
    h[2] = (_Float16)x[2]; h[3] = (_Float16)x[3];
    return h;
}

__global__ __launch_bounds__(THREADS, 2)
void gemm_lse_kernel(const float* __restrict__ A,   // [256][256]
                     const float* __restrict__ F,   // [131072][256]
                     float* __restrict__ partial)   // [256][NBLOCKS]
{
    __shared__ __align__(16) char lds[FBUF_OFF + 2 * FBUF_SZ];  // 160 KB

    const int tid  = threadIdx.x;
    const int lane = tid & 63;
    const int w    = tid >> 6;        // wave 0..7 -> batch rows w*32..+31
    const int m    = lane & 31;       // MFMA row/col within 32
    const int hi   = lane >> 5;       // k-half 0/1
    const int fblk = blockIdx.x;      // feature superblock (512 features)

    char* fbuf0 = lds + FBUF_OFF;
    char* fbuf1 = fbuf0 + FBUF_SZ;

    // staging geometry: wave w stages F rows p*32 + w*4 + i (i=0..3);
    // lane l covers 16B (f32x4) of the 1KB row -> one fully-coalesced
    // global_load_dwordx4 per row per instruction.
    const float* fstage = F + ((size_t)fblk * 512 + w * 4) * DDIM + lane * 4;
    const int ckl = lane >> 1;              // lane's f16 16B-chunk index (0..31)
    const int lhalf = (lane & 1) << 3;      // low/high 8B of the chunk

    // ---- issue F loads for pass 0 (hide under inputs staging) ----
    float4v sN[4];
#pragma unroll
    for (int i = 0; i < 4; i++)
        sN[i] = *(const float4v*)(fstage + (size_t)i * DDIM);

    // ---- stage ALL 256 input rows into LDS as f16, swizzled ----
    // wave-instruction j stages row j*8+w contiguously (lane l = f32[4l..4l+4));
    // 4 groups of 8 rows to bound live registers; j = g*8+i in 0..31 ->
    // rows cover 0..255 (R12 bug: only 2 groups -> rows 0..127).
#pragma unroll
    for (int g = 0; g < 4; g++) {
        float4v x[8];
#pragma unroll
        for (int i = 0; i < 8; i++)
            x[i] = *(const float4v*)(A + (size_t)((g * 8 + i) * 8 + w) * DDIM + lane * 4);
#pragma unroll
        for (int i = 0; i < 8; i++) {
            const int rr = (g * 8 + i) * 8 + w;
            *(half4v*)(lds + rr * ROWB + (((ckl ^ (rr & 7)) << 4) | lhalf)) = cvt4(x[i]);
        }
    }

    // ---- write pass-0 F tile (sN had the whole inputs stage to land) ----
#pragma unroll
    for (int i = 0; i < 4; i++) {
        const int fr = w * 4 + i;
        *(half4v*)(fbuf0 + fr * ROWB + (((ckl ^ (fr & 7)) << 4) | lhalf)) = cvt4(sN[i]);
    }
    __syncthreads();

    // ---- pull this lane's inputs row chunks into registers (held forever)
    // B-frag for kb step: inputs[w*32+m][k = kb*16 + hi*8 + j] = chunk 2kb+hi
    half8 brow[16];
    {
        const char* myrow = lds + (w * 32 + m) * ROWB;
        const int swm = m & 7;        // (w*32+m)&7 == m&7
#pragma unroll
        for (int kb = 0; kb < 16; kb++)
            brow[kb] = *(const half8*)(myrow + (((2 * kb + hi) ^ swm) << 4));
    }

    float rs0 = 0.f, rs1 = 0.f;
    const int sw = m & 7;
    const char* pA0 = fbuf0 + m * ROWB;   // F-tile row for this lane
    const char* pA1 = fbuf1 + m * ROWB;

    // 16 passes of 32 features; double-buffered; distance-1 issue-at-top.
#pragma unroll 1
    for (int p = 0; p < 16; p++) {
        // (a) issue coalesced global loads for pass p+1
        if (p + 1 < 16) {
#pragma unroll
            for (int i = 0; i < 4; i++)
                sN[i] = *(const float4v*)(fstage + (size_t)((p + 1) * 32 + i) * DDIM);
        }

        // (b) compute pass p from LDS F-tile + register brow
        const char* pA = (p & 1) ? pA1 : pA0;
        float16v acc;
#pragma unroll
        for (int i = 0; i < 16; i++) acc[i] = 0.f;

        half8 afc = *(const half8*)(pA + ((hi ^ sw) << 4));   // kb=0 chunk
#pragma unroll
        for (int kb = 0; kb < 16; kb++) {
            half8 afn;
            if (kb < 15)
                afn = *(const half8*)(pA + (((2 * (kb + 1) + hi) ^ sw) << 4));
            acc = __builtin_amdgcn_mfma_f32_32x32x16_f16(afc, brow[kb], acc, 0, 0, 0);
            afc = afn;
        }

        // exp(logit-20) fold; only col=lane&31 (batch) identity is consumed
#pragma unroll
        for (int i = 0; i < 16; i += 2) {
            rs0 += __expf(fmaf(acc[i], 20.f, -20.f));
            rs1 += __expf(fmaf(acc[i + 1], 20.f, -20.f));
        }

        // keep the cvt + vmcnt wait BELOW the compute (no hoisting)
        __builtin_amdgcn_sched_barrier(0);

        // (c) wait + write pass p+1 tile into the other buffer
        if (p + 1 < 16) {
            char* fb = (p & 1) ? fbuf0 : fbuf1;
#pragma unroll
            for (int i = 0; i < 4; i++) {
                const int fr = w * 4 + i;
                *(half4v*)(fb + fr * ROWB + (((ckl ^ (fr & 7)) << 4) | lhalf)) = cvt4(sN[i]);
            }
            // (d) barrier: vmcnt already 0 (consumed above) -> no drain stall
            __syncthreads();
        }
    }

    // fold feature halves (lanes l, l^32 hold complementary feature rows)
    float rowsum = rs0 + rs1;
    rowsum += __shfl_xor(rowsum, 32);
    if (hi == 0)
        partial[(size_t)(w * 32 + m) * NBLOCKS + fblk] = rowsum;
}

// One block per batch row, 64 threads: per-row CE terms -> ce[b] = {cem, ceh}.
__global__ __launch_bounds__(64)
void finalize_rows(const float* __restrict__ partial,  // [256][NBLOCKS]
                   const float* __restrict__ A,
                   const float* __restrict__ F,
                   const int* __restrict__ targets,
                   float2v* __restrict__ ce)           // [256]
{
    const int b = blockIdx.x;
    const int l = threadIdx.x;   // 0..63

    // partials row: 256 floats; lane l sums one float4.
    // p4[0..31] = mean half (blocks 0..127), p4[32..63] = hard half.
    const float4v* p4 = (const float4v*)(partial + b * NBLOCKS);
    const float4v x = p4[l];
    const float s = x[0] + x[1] + x[2] + x[3];
    float smv = (l < 32) ? s : 0.f;
    float shv = (l < 32) ? 0.f : s;

    // target-logit dots: lane l covers D-elements [4l, 4l+4)
    const int t = targets[b];
    const float4v a  = *(const float4v*)(A + b * DDIM + l * 4);
    const float4v xm = *(const float4v*)(F + (size_t)t * DDIM + l * 4);
    const float4v xh = *(const float4v*)(F + (size_t)(t + NHALF) * DDIM + l * 4);
    float dm = a[0] * xm[0] + a[1] * xm[1] + a[2] * xm[2] + a[3] * xm[3];
    float dh = a[0] * xh[0] + a[1] * xh[1] + a[2] * xh[2] + a[3] * xh[3];

#pragma unroll
    for (int msk = 1; msk < 64; msk <<= 1) {
        smv += __shfl_xor(smv, msk);
        shv += __shfl_xor(shv, msk);
        dm  += __shfl_xor(dm, msk);
        dh  += __shfl_xor(dh, msk);
    }
    if (l == 0) {
        // CE = LSE - target_logit ; LSE = 20 + ln(sum of exp(logit-20))
        float2v r;
        r[0] = 20.f + __logf(smv) - dm * 20.f;
        r[1] = 20.f + __logf(shv) - dh * 20.f;
        ce[b] = r;
    }
}

__global__ __launch_bounds__(256)
void finalize_loss(const float2v* __restrict__ ce,  // [256]
                   float* __restrict__ out)
{
    const float2v c = ce[threadIdx.x];
    float cem = c[0], ceh = c[1];
#pragma unroll
    for (int msk = 1; msk < 64; msk <<= 1) {
        cem += __shfl_xor(cem, msk);
        ceh += __shfl_xor(ceh, msk);
    }
    __shared__ float sb[8];
    const int wv = threadIdx.x >> 6;
    if ((threadIdx.x & 63) == 0) { sb[wv] = cem; sb[4 + wv] = ceh; }
    __syncthreads();
    if (threadIdx.x == 0) {
        const float cm = (sb[0] + sb[1] + sb[2] + sb[3]) * (1.f / 256.f);
        const float ch = (sb[4] + sb[5] + sb[6] + sb[7]) * (1.f / 256.f);
        const float rl = cm - 0.2f;
        out[0] = 0.5f * (ch + (rl > 0.f ? rl : 0.f));
    }
}

extern "C" void kernel_launch(void* const* d_in, const int* in_sizes, int n_in,
                              void* d_out, int out_size, void* d_ws, size_t ws_size,
                              hipStream_t stream) {
    const float* inputs   = (const float*)d_in[0];   // [256,256] f32
    const int*   targets  = (const int*)d_in[1];     // [256] int
    const float* features = (const float*)d_in[2];   // [131072,256] f32
    float* out = (float*)d_out;
    float* partial = (float*)d_ws;                   // 256*NBLOCKS floats = 256 KB
    float2v* ce = (float2v*)((char*)d_ws + BROWS * NBLOCKS * sizeof(float)); // 2 KB

    gemm_lse_kernel<<<NBLOCKS, THREADS, 0, stream>>>(inputs, features, partial);
    finalize_rows<<<BROWS, 64, 0, stream>>>(partial, inputs, features, targets, ce);
    finalize_loss<<<1, 256, 0, stream>>>(ce, out);
}